// Round 1
// baseline (242.525 us; speedup 1.0000x reference)
//
#include <hip/hip_runtime.h>
#include <math.h>

#define U_ 4096
#define T_ 200
#define K_ 64
#define Q_ 10000
#define H_ 128

__device__ __forceinline__ float gelu_f(float x) {
  // exact erf GELU (matches jax.nn.gelu approximate=False)
  return 0.5f * x * (1.0f + erff(x * 0.70710678118654752440f));
}

// ---------------------------------------------------------------------------
// K1: MLP table over (q, resp) in [0,Q)x{0,1}  -> r_table, mu_table
//     plus fused kc_of_q = argmax_k kmap[q][k] (one-hot)
// 1250 blocks x 256; each block does exactly 16 pairs.
// W2 staged in LDS in two 32KB halves (keeps static LDS <= 40KB).
// ---------------------------------------------------------------------------
__global__ __launch_bounds__(256) void mlp_table_kernel(
    const float* __restrict__ diff_mu, const float* __restrict__ disc_mu,
    const float* __restrict__ W1, const float* __restrict__ b1,
    const float* __restrict__ W2, const float* __restrict__ b2,
    const float* __restrict__ W3, const float* __restrict__ b3,
    const unsigned char* __restrict__ kmap,
    float* __restrict__ r_table, float* __restrict__ mu_table,
    int* __restrict__ kc_of_q) {
  __shared__ float W2s[64 * H_];     // 32 KB: one half of W2 at a time
  __shared__ float h1buf[16][H_];    // 8 KB: h1 for the block's 16 pairs

  const int tid = threadIdx.x;
  const int base = blockIdx.x * 16;  // global pair base; 1250*16 = 20000 exact

  // stage first half of W2 (rows k=0..63), coalesced
  for (int v = tid; v < 64 * H_; v += 256) W2s[v] = W2[v];

  // fused kc_of_q: first 40 blocks cover Q=10000 questions
  if (blockIdx.x < 40) {
    int q = blockIdx.x * 256 + tid;
    if (q < Q_) {
      const unsigned char* km = kmap + (size_t)q * K_;
      int kc = 0;
#pragma unroll
      for (int k = 0; k < K_; ++k)
        if (km[k]) kc = k;  // one-hot -> the single set index
      kc_of_q[q] = kc;
    }
  }

  // layer 1: h1[pair][j] for 16 pairs x 128 hidden
  for (int v = tid; v < 16 * H_; v += 256) {
    int pl = v >> 7, j = v & 127;
    int pg = base + pl;
    int q = pg >> 1;
    float rf = (float)(pg & 1);
    float td = diff_mu[q], ts = disc_mu[q];
    float a = b1[j];
    a += td * W1[j];
    a += ts * W1[H_ + j];
    a += rf * W1[2 * H_ + j];
    h1buf[pl][j] = gelu_f(a);
  }
  __syncthreads();

  // layer 2: wave w handles pairs 4w..4w+3; lane j computes outputs j, j+64
  const int w = tid >> 6, lane = tid & 63;
  float a0[4] = {0.f, 0.f, 0.f, 0.f}, a1[4] = {0.f, 0.f, 0.f, 0.f};

  for (int k = 0; k < 64; ++k) {
    float w0 = W2s[k * H_ + lane];        // 2-way bank alias: free
    float w1 = W2s[k * H_ + lane + 64];
#pragma unroll
    for (int p = 0; p < 4; ++p) {
      float hv = h1buf[w * 4 + p][k];     // uniform -> broadcast
      a0[p] = fmaf(w0, hv, a0[p]);
      a1[p] = fmaf(w1, hv, a1[p]);
    }
  }
  __syncthreads();
  // stage second half of W2 (rows k=64..127)
  for (int v = tid; v < 64 * H_; v += 256) W2s[v] = W2[64 * H_ + v];
  __syncthreads();
  for (int k = 0; k < 64; ++k) {
    float w0 = W2s[k * H_ + lane];
    float w1 = W2s[k * H_ + lane + 64];
#pragma unroll
    for (int p = 0; p < 4; ++p) {
      float hv = h1buf[w * 4 + p][64 + k];
      a0[p] = fmaf(w0, hv, a0[p]);
      a1[p] = fmaf(w1, hv, a1[p]);
    }
  }

  // layer 3 + head math
  float w30a = W3[lane * 2 + 0], w31a = W3[lane * 2 + 1];
  float w30b = W3[(lane + 64) * 2 + 0], w31b = W3[(lane + 64) * 2 + 1];
  float b2a = b2[lane], b2b = b2[lane + 64];
  float b30 = b3[0], b31 = b3[1];
#pragma unroll
  for (int p = 0; p < 4; ++p) {
    float h2a = gelu_f(a0[p] + b2a);
    float h2b = gelu_f(a1[p] + b2b);
    float s0 = h2a * w30a + h2b * w30b;
    float s1 = h2a * w31a + h2b * w31b;
#pragma unroll
    for (int off = 32; off > 0; off >>= 1) {
      s0 += __shfl_xor(s0, off, 64);
      s1 += __shfl_xor(s1, off, 64);
    }
    if (lane == 0) {
      float mu = gelu_f(s0 + b30);
      float lv = gelu_f(s1 + b31);
      float sd = fmaxf(expf(0.5f * lv), 1e-8f);
      int pg = base + w * 4 + p;
      mu_table[pg] = mu;
      r_table[pg] = 1.0f / (sd * sd);  // (STD_THETA/std)^2, STD_THETA=1
    }
  }
}

// ---------------------------------------------------------------------------
// K2: per-trial gather into transposed (T,U) layout for the scans.
// idx = t*U + u  (U=4096 = 2^12). Writes coalesced; q_id reads stride-T but
// fully L2-resident (3.3 MB).
// ---------------------------------------------------------------------------
__global__ __launch_bounds__(256) void gather_kernel(
    const int* __restrict__ q_id, const int* __restrict__ resp,
    const float* __restrict__ diff_mu, const float* __restrict__ disc_mu,
    const float* __restrict__ r_table, const float* __restrict__ mu_table,
    const int* __restrict__ kc_of_q,
    float2* __restrict__ rm, float2* __restrict__ tstd,
    int* __restrict__ kcb) {
  int idx = blockIdx.x * 256 + threadIdx.x;  // < 819200
  int u = idx & (U_ - 1);
  int t = idx >> 12;
  int q = q_id[u * T_ + t];
  int rp = resp[u * T_ + t];
  int p = q * 2 + rp;
  rm[idx] = make_float2(r_table[p], mu_table[p]);
  tstd[idx] = make_float2(disc_mu[q], diff_mu[q]);  // (ts, td)
  kcb[idx] = kc_of_q[q];
}

// ---------------------------------------------------------------------------
// K3a: backward recursion, lane-per-user. 64 blocks x 64 threads spread over
// CUs. Double-buffered 8-step chunks hide L2 latency behind the div chain.
// ---------------------------------------------------------------------------
__global__ __launch_bounds__(64) void backward_kernel(
    const float2* __restrict__ rm, float2* __restrict__ bc) {
  const int u = blockIdx.x * 64 + threadIdx.x;
  float b = 1.0f, c = 0.0f;
  constexpr int CH = 8;  // T_ = 200 = 25 chunks
  float2 A[CH], B[CH];

  auto loadCh = [&](float2* buf, int ci) {
    int t0 = ci * CH;
#pragma unroll
    for (int i = 0; i < CH; ++i) buf[i] = rm[(t0 + i) * U_ + u];
  };
  auto compCh = [&](const float2* buf, int ci) {
    int t0 = ci * CH;
#pragma unroll
    for (int i = CH - 1; i >= 0; --i) {
      float rt = buf[i].x, mt = buf[i].y;
      b = 1.0f / ((1.0f + rt) + (1.0f - b));  // reference association
      c = b * fmaf(rt, mt, c);
      bc[(t0 + i) * U_ + u] = make_float2(b, c);
    }
  };

  loadCh(A, 24);
  for (int ci = 24; ci >= 2; ci -= 2) {
    loadCh(B, ci - 1);
    compCh(A, ci);
    loadCh(A, ci - 2);
    compCh(B, ci - 1);
  }
  compCh(A, 0);
}

// ---------------------------------------------------------------------------
// K3b: forward recursion, wave-per-user. Lane k holds KC-state k in a
// register; prev = shfl(curr, kc). 4096 waves -> 4 waves/SIMD. Logits are
// banked one-per-lane and stored coalesced every 64 steps.
// ---------------------------------------------------------------------------
__global__ __launch_bounds__(256) void forward_kernel(
    const float2* __restrict__ bc, const int* __restrict__ kcb,
    const float2* __restrict__ tstd, float* __restrict__ out) {
  int gt = blockIdx.x * 256 + threadIdx.x;
  int lane = threadIdx.x & 63;
  int u = __builtin_amdgcn_readfirstlane(gt >> 6);  // wave id == user id

  float curr = 0.0f;   // ability state for KC == lane
  float lsave = 0.0f;
  float* logits = out;
  float* last = out + (size_t)U_ * T_;

  for (int t0 = 0; t0 < T_; t0 += 64) {
    int nt = min(64, T_ - t0);
#pragma unroll 8
    for (int s = 0; s < nt; ++s) {
      int t = t0 + s;
      float2 bcv = bc[t * U_ + u];    // uniform -> broadcast/scalar load
      int kc = kcb[t * U_ + u];
      float2 tv = tstd[t * U_ + u];
      float prev = __shfl(curr, kc, 64);
      float ab = fmaf(bcv.x, prev, bcv.y);
      if (lane == kc) curr = ab;
      if (lane == s) lsave = tv.x * (ab - tv.y);  // ts*(ability - td)
    }
    if (lane < nt) logits[u * T_ + t0 + lane] = lsave;
  }
  last[u * K_ + lane] = curr;  // last_ability_kc (U,K)
}

// ---------------------------------------------------------------------------
extern "C" void kernel_launch(void* const* d_in, const int* in_sizes, int n_in,
                              void* d_out, int out_size, void* d_ws,
                              size_t ws_size, hipStream_t stream) {
  // setup_inputs order:
  // 0 mask(bool,U*T) 1 q_id(i32) 2 kmap(bool,Q*K) 3 resp(i32)
  // 4 diff_mu(f32,Q) 5 disc_mu(f32,Q) 6 W1(3*H) 7 b1(H) 8 W2(H*H) 9 b2(H)
  // 10 W3(H*2) 11 b3(2)
  const int* q_id = (const int*)d_in[1];
  const unsigned char* kmap = (const unsigned char*)d_in[2];
  const int* resp = (const int*)d_in[3];
  const float* diff_mu = (const float*)d_in[4];
  const float* disc_mu = (const float*)d_in[5];
  const float* W1 = (const float*)d_in[6];
  const float* b1 = (const float*)d_in[7];
  const float* W2 = (const float*)d_in[8];
  const float* b2 = (const float*)d_in[9];
  const float* W3 = (const float*)d_in[10];
  const float* b3 = (const float*)d_in[11];
  float* out = (float*)d_out;
  char* ws = (char*)d_ws;

  auto align512 = [](size_t x) { return (x + 511) & ~(size_t)511; };
  size_t o = 0;
  float* r_table = (float*)(ws + o);  o = align512(o + (size_t)2 * Q_ * 4);
  float* mu_table = (float*)(ws + o); o = align512(o + (size_t)2 * Q_ * 4);
  int* kc_of_q = (int*)(ws + o);      o = align512(o + (size_t)Q_ * 4);
  float2* rm = (float2*)(ws + o);     o = align512(o + (size_t)U_ * T_ * 8);
  float2* tstd = (float2*)(ws + o);   o = align512(o + (size_t)U_ * T_ * 8);
  int* kcb = (int*)(ws + o);          o = align512(o + (size_t)U_ * T_ * 4);
  float2* bcb = (float2*)(ws + o);    o = align512(o + (size_t)U_ * T_ * 8);
  (void)ws_size; (void)in_sizes; (void)n_in; (void)out_size;

  mlp_table_kernel<<<1250, 256, 0, stream>>>(diff_mu, disc_mu, W1, b1, W2, b2,
                                             W3, b3, kmap, r_table, mu_table,
                                             kc_of_q);
  gather_kernel<<<(U_ * T_) / 256, 256, 0, stream>>>(
      q_id, resp, diff_mu, disc_mu, r_table, mu_table, kc_of_q, rm, tstd, kcb);
  backward_kernel<<<U_ / 64, 64, 0, stream>>>(rm, bcb);
  forward_kernel<<<(U_ / 4), 256, 0, stream>>>(bcb, kcb, tstd, out);
}

// Round 3
// 190.841 us; speedup vs baseline: 1.2708x; 1.2708x over previous
//
#include <hip/hip_runtime.h>
#include <math.h>

#define U_ 4096
#define T_ 200
#define K_ 64
#define Q_ 10000
#define H_ 128

__device__ __forceinline__ float gelu_f(float x) {
  // exact erf GELU (matches jax.nn.gelu approximate=False)
  return 0.5f * x * (1.0f + erff(x * 0.70710678118654752440f));
}

__device__ __forceinline__ float rlanef(float v, int l) {
  return __int_as_float(__builtin_amdgcn_readlane(__float_as_int(v), l));
}
__device__ __forceinline__ int rlanei(int v, int l) {
  return __builtin_amdgcn_readlane(v, l);
}

// ---------------------------------------------------------------------------
// K1: MLP table over (q, resp) -> tab4[2q+rp] = (r, mu, ts, td)
//     plus fused kc_of_q = argmax_k kmap[q][k] (one-hot).
// 1250 blocks x 256; each block does exactly 16 pairs. W2 staged in LDS in
// two 32KB halves.
// ---------------------------------------------------------------------------
__global__ __launch_bounds__(256) void mlp_table_kernel(
    const float* __restrict__ diff_mu, const float* __restrict__ disc_mu,
    const float* __restrict__ W1, const float* __restrict__ b1,
    const float* __restrict__ W2, const float* __restrict__ b2,
    const float* __restrict__ W3, const float* __restrict__ b3,
    const unsigned char* __restrict__ kmap,
    float4* __restrict__ tab4, int* __restrict__ kc_of_q) {
  __shared__ float W2s[64 * H_];     // 32 KB: one half of W2 at a time
  __shared__ float h1buf[16][H_];    // 8 KB: h1 for the block's 16 pairs

  const int tid = threadIdx.x;
  const int base = blockIdx.x * 16;  // 1250*16 = 20000 exact

  for (int v = tid; v < 64 * H_; v += 256) W2s[v] = W2[v];

  if (blockIdx.x < 40) {
    int q = blockIdx.x * 256 + tid;
    if (q < Q_) {
      const unsigned char* km = kmap + (size_t)q * K_;
      int kc = 0;
#pragma unroll
      for (int k = 0; k < K_; ++k)
        if (km[k]) kc = k;  // one-hot -> single set index
      kc_of_q[q] = kc;
    }
  }

  // layer 1
  for (int v = tid; v < 16 * H_; v += 256) {
    int pl = v >> 7, j = v & 127;
    int pg = base + pl;
    int q = pg >> 1;
    float rf = (float)(pg & 1);
    float td = diff_mu[q], ts = disc_mu[q];
    float a = b1[j];
    a += td * W1[j];
    a += ts * W1[H_ + j];
    a += rf * W1[2 * H_ + j];
    h1buf[pl][j] = gelu_f(a);
  }
  __syncthreads();

  // layer 2: wave w handles pairs 4w..4w+3; lane j -> outputs j, j+64
  const int w = tid >> 6, lane = tid & 63;
  float a0[4] = {0.f, 0.f, 0.f, 0.f}, a1[4] = {0.f, 0.f, 0.f, 0.f};

  for (int k = 0; k < 64; ++k) {
    float w0 = W2s[k * H_ + lane];
    float w1 = W2s[k * H_ + lane + 64];
#pragma unroll
    for (int p = 0; p < 4; ++p) {
      float hv = h1buf[w * 4 + p][k];
      a0[p] = fmaf(w0, hv, a0[p]);
      a1[p] = fmaf(w1, hv, a1[p]);
    }
  }
  __syncthreads();
  for (int v = tid; v < 64 * H_; v += 256) W2s[v] = W2[64 * H_ + v];
  __syncthreads();
  for (int k = 0; k < 64; ++k) {
    float w0 = W2s[k * H_ + lane];
    float w1 = W2s[k * H_ + lane + 64];
#pragma unroll
    for (int p = 0; p < 4; ++p) {
      float hv = h1buf[w * 4 + p][64 + k];
      a0[p] = fmaf(w0, hv, a0[p]);
      a1[p] = fmaf(w1, hv, a1[p]);
    }
  }

  // layer 3 + head math
  float w30a = W3[lane * 2 + 0], w31a = W3[lane * 2 + 1];
  float w30b = W3[(lane + 64) * 2 + 0], w31b = W3[(lane + 64) * 2 + 1];
  float b2a = b2[lane], b2b = b2[lane + 64];
  float b30 = b3[0], b31 = b3[1];
#pragma unroll
  for (int p = 0; p < 4; ++p) {
    float h2a = gelu_f(a0[p] + b2a);
    float h2b = gelu_f(a1[p] + b2b);
    float s0 = h2a * w30a + h2b * w30b;
    float s1 = h2a * w31a + h2b * w31b;
#pragma unroll
    for (int off = 32; off > 0; off >>= 1) {
      s0 += __shfl_xor(s0, off, 64);
      s1 += __shfl_xor(s1, off, 64);
    }
    if (lane == 0) {
      float mu = gelu_f(s0 + b30);
      float lv = gelu_f(s1 + b31);
      float sd = fmaxf(expf(0.5f * lv), 1e-8f);
      int pg = base + w * 4 + p;
      int q = pg >> 1;
      tab4[pg] = make_float4(1.0f / (sd * sd), mu, disc_mu[q], diff_mu[q]);
    }
  }
}

// ---------------------------------------------------------------------------
// K2: fused gather + backward + forward scan. Wave per user (4096 waves,
// 16/CU). All per-step data pre-gathered into registers (lane s holds step
// i*64+s); chains use readlane + per-lane select only — no global load in
// any chain.
// ---------------------------------------------------------------------------
__global__ __launch_bounds__(256) void scan_kernel(
    const int* __restrict__ q_id, const int* __restrict__ resp,
    const float4* __restrict__ tab4, const int* __restrict__ kc_of_q,
    float* __restrict__ out) {
  const int lane = threadIdx.x & 63;
  const int u = (blockIdx.x << 2) | (threadIdx.x >> 6);  // wave id == user

  // ---- phase 0: gather 200 steps into 4 register tiles (tail tile = 8) ----
  float tr[4], tmu[4], tts[4], ttd[4];
  int tkc[4];
#pragma unroll
  for (int i = 0; i < 4; ++i) {
    int t = i * 64 + lane;
    int tc = t < T_ ? t : T_ - 1;       // clamp: avoids OOB; lanes>=8 of tile3 unused
    int q = q_id[u * T_ + tc];          // coalesced
    int rp = resp[u * T_ + tc];         // coalesced
    float4 f = tab4[q * 2 + rp];        // L2-resident 320KB table
    tr[i] = f.x;   // r
    tmu[i] = f.y;  // mu
    tts[i] = f.z;  // ts
    ttd[i] = f.w;  // td
    tkc[i] = kc_of_q[q];
  }

  // ---- phase 1: backward recursion t = 199..0 (wave-scalar chain) ----
  // b_t = 1/(2 + r_t - b_next); c_t = b_t*(c_next + r_t*mu_t)
  // results overwrite (tr, tmu) in place at lane t%64 (cndmask writeback —
  // no writelane builtin on this toolchain).
  float b = 1.0f, c = 0.0f;
#define BWD_STEP(i, s)                                   \
  {                                                      \
    float r_ = rlanef(tr[i], s);                         \
    float m_ = rlanef(tmu[i], s);                        \
    float x_ = 2.0f + r_ - b;                            \
    float ib = __builtin_amdgcn_rcpf(x_);                \
    ib = ib * (2.0f - x_ * ib); /* Newton step */        \
    b = ib;                                              \
    c = b * fmaf(r_, m_, c);                             \
    tr[i] = (lane == (s)) ? b : tr[i];                   \
    tmu[i] = (lane == (s)) ? c : tmu[i];                 \
  }
#pragma unroll
  for (int s = 7; s >= 0; --s) BWD_STEP(3, s)
#pragma unroll
  for (int s = 63; s >= 0; --s) BWD_STEP(2, s)
#pragma unroll
  for (int s = 63; s >= 0; --s) BWD_STEP(1, s)
#pragma unroll
  for (int s = 63; s >= 0; --s) BWD_STEP(0, s)
#undef BWD_STEP

  // ---- phase 2: forward KC scan t = 0..199 (wave-scalar chain) ----
  // lane k holds ability state of KC k; prev = readlane(curr, kc).
  float curr = 0.0f;
  float* logits = out;
  float* last = out + (size_t)U_ * T_;

#define FWD_STEP(i, s)                                    \
  {                                                       \
    float b_ = rlanef(tr[i], s);                          \
    float c_ = rlanef(tmu[i], s);                         \
    int kc_ = rlanei(tkc[i], s);                          \
    float ts_ = rlanef(tts[i], s);                        \
    float td_ = rlanef(ttd[i], s);                        \
    float prev = rlanef(curr, kc_);                       \
    float ab = fmaf(b_, prev, c_);                        \
    curr = (lane == kc_) ? ab : curr;                     \
    float lg = ts_ * (ab - td_);                          \
    lsave = (lane == (s)) ? lg : lsave;                   \
  }
  {
    float lsave = 0.0f;
#pragma unroll
    for (int s = 0; s < 64; ++s) FWD_STEP(0, s)
    logits[u * T_ + lane] = lsave;
  }
  {
    float lsave = 0.0f;
#pragma unroll
    for (int s = 0; s < 64; ++s) FWD_STEP(1, s)
    logits[u * T_ + 64 + lane] = lsave;
  }
  {
    float lsave = 0.0f;
#pragma unroll
    for (int s = 0; s < 64; ++s) FWD_STEP(2, s)
    logits[u * T_ + 128 + lane] = lsave;
  }
  {
    float lsave = 0.0f;
#pragma unroll
    for (int s = 0; s < 8; ++s) FWD_STEP(3, s)
    if (lane < 8) logits[u * T_ + 192 + lane] = lsave;
  }
#undef FWD_STEP

  last[u * K_ + lane] = curr;  // last_ability_kc (U, K=64)
}

// ---------------------------------------------------------------------------
extern "C" void kernel_launch(void* const* d_in, const int* in_sizes, int n_in,
                              void* d_out, int out_size, void* d_ws,
                              size_t ws_size, hipStream_t stream) {
  // setup_inputs order:
  // 0 mask 1 q_id(i32,U*T) 2 kmap(bool,Q*K) 3 resp(i32) 4 diff_mu 5 disc_mu
  // 6 W1 7 b1 8 W2 9 b2 10 W3 11 b3
  const int* q_id = (const int*)d_in[1];
  const unsigned char* kmap = (const unsigned char*)d_in[2];
  const int* resp = (const int*)d_in[3];
  const float* diff_mu = (const float*)d_in[4];
  const float* disc_mu = (const float*)d_in[5];
  const float* W1 = (const float*)d_in[6];
  const float* b1 = (const float*)d_in[7];
  const float* W2 = (const float*)d_in[8];
  const float* b2 = (const float*)d_in[9];
  const float* W3 = (const float*)d_in[10];
  const float* b3 = (const float*)d_in[11];
  float* out = (float*)d_out;
  char* ws = (char*)d_ws;

  auto align512 = [](size_t x) { return (x + 511) & ~(size_t)511; };
  size_t o = 0;
  float4* tab4 = (float4*)(ws + o);  o = align512(o + (size_t)2 * Q_ * 16);
  int* kc_of_q = (int*)(ws + o);     o = align512(o + (size_t)Q_ * 4);
  (void)ws_size; (void)in_sizes; (void)n_in; (void)out_size;

  mlp_table_kernel<<<1250, 256, 0, stream>>>(diff_mu, disc_mu, W1, b1, W2, b2,
                                             W3, b3, kmap, tab4, kc_of_q);
  scan_kernel<<<U_ / 4, 256, 0, stream>>>(q_id, resp, tab4, kc_of_q, out);
}

// Round 4
// 153.857 us; speedup vs baseline: 1.5763x; 1.2404x over previous
//
#include <hip/hip_runtime.h>
#include <math.h>

#define U_ 4096
#define T_ 200
#define K_ 64
#define Q_ 10000
#define H_ 128

__device__ __forceinline__ float gelu_f(float x) {
  // exact erf GELU (matches jax.nn.gelu approximate=False)
  return 0.5f * x * (1.0f + erff(x * 0.70710678118654752440f));
}

__device__ __forceinline__ float rlanef(float v, int l) {
  return __int_as_float(__builtin_amdgcn_readlane(__float_as_int(v), l));
}
__device__ __forceinline__ int rlanei(int v, int l) {
  return __builtin_amdgcn_readlane(v, l);
}

// ---------------------------------------------------------------------------
// K1: MLP table over (q, resp) -> tab4[2q+rp] = (r, mu, ts, td)
//     plus fused kc_of_q = argmax_k kmap[q][k] (one-hot).
// 1250 blocks x 256; each block does exactly 16 pairs. W2 staged in LDS in
// two 32KB halves.
// R4 fix: launch_bounds(256,4) caps VGPR at 128 (R3 measured VGPR=256 with
// ~6MB scratch spill -> 10% occupancy, 68us). unroll_count(8) keeps the
// unroller inside the register budget.
// ---------------------------------------------------------------------------
__global__ __launch_bounds__(256, 4) void mlp_table_kernel(
    const float* __restrict__ diff_mu, const float* __restrict__ disc_mu,
    const float* __restrict__ W1, const float* __restrict__ b1,
    const float* __restrict__ W2, const float* __restrict__ b2,
    const float* __restrict__ W3, const float* __restrict__ b3,
    const unsigned char* __restrict__ kmap,
    float4* __restrict__ tab4, int* __restrict__ kc_of_q) {
  __shared__ float W2s[64 * H_];     // 32 KB: one half of W2 at a time
  __shared__ float h1buf[16][H_];    // 8 KB: h1 for the block's 16 pairs

  const int tid = threadIdx.x;
  const int base = blockIdx.x * 16;  // 1250*16 = 20000 exact

  for (int v = tid; v < 64 * H_; v += 256) W2s[v] = W2[v];

  if (blockIdx.x < 40) {
    int q = blockIdx.x * 256 + tid;
    if (q < Q_) {
      const unsigned char* km = kmap + (size_t)q * K_;
      int kc = 0;
#pragma unroll
      for (int k = 0; k < K_; ++k)
        if (km[k]) kc = k;  // one-hot -> single set index
      kc_of_q[q] = kc;
    }
  }

  // layer 1
  for (int v = tid; v < 16 * H_; v += 256) {
    int pl = v >> 7, j = v & 127;
    int pg = base + pl;
    int q = pg >> 1;
    float rf = (float)(pg & 1);
    float td = diff_mu[q], ts = disc_mu[q];
    float a = b1[j];
    a += td * W1[j];
    a += ts * W1[H_ + j];
    a += rf * W1[2 * H_ + j];
    h1buf[pl][j] = gelu_f(a);
  }
  __syncthreads();

  // layer 2: wave w handles pairs 4w..4w+3; lane j -> outputs j, j+64
  const int w = tid >> 6, lane = tid & 63;
  float a0[4] = {0.f, 0.f, 0.f, 0.f}, a1[4] = {0.f, 0.f, 0.f, 0.f};
  const float* h1w = &h1buf[w * 4][0];

#pragma clang loop unroll_count(8)
  for (int k = 0; k < 64; ++k) {
    float w0 = W2s[k * H_ + lane];       // banks j%32: 2-way alias, free
    float w1 = W2s[k * H_ + lane + 64];
#pragma unroll
    for (int p = 0; p < 4; ++p) {
      float hv = h1w[p * H_ + k];        // wave-uniform -> broadcast
      a0[p] = fmaf(w0, hv, a0[p]);
      a1[p] = fmaf(w1, hv, a1[p]);
    }
  }
  __syncthreads();
  for (int v = tid; v < 64 * H_; v += 256) W2s[v] = W2[64 * H_ + v];
  __syncthreads();
#pragma clang loop unroll_count(8)
  for (int k = 0; k < 64; ++k) {
    float w0 = W2s[k * H_ + lane];
    float w1 = W2s[k * H_ + lane + 64];
#pragma unroll
    for (int p = 0; p < 4; ++p) {
      float hv = h1w[p * H_ + 64 + k];
      a0[p] = fmaf(w0, hv, a0[p]);
      a1[p] = fmaf(w1, hv, a1[p]);
    }
  }

  // layer 3 + head math
  float w30a = W3[lane * 2 + 0], w31a = W3[lane * 2 + 1];
  float w30b = W3[(lane + 64) * 2 + 0], w31b = W3[(lane + 64) * 2 + 1];
  float b2a = b2[lane], b2b = b2[lane + 64];
  float b30 = b3[0], b31 = b3[1];
#pragma unroll
  for (int p = 0; p < 4; ++p) {
    float h2a = gelu_f(a0[p] + b2a);
    float h2b = gelu_f(a1[p] + b2b);
    float s0 = h2a * w30a + h2b * w30b;
    float s1 = h2a * w31a + h2b * w31b;
#pragma unroll
    for (int off = 32; off > 0; off >>= 1) {
      s0 += __shfl_xor(s0, off, 64);
      s1 += __shfl_xor(s1, off, 64);
    }
    if (lane == 0) {
      float mu = gelu_f(s0 + b30);
      float lv = gelu_f(s1 + b31);
      float sd = fmaxf(expf(0.5f * lv), 1e-8f);
      int pg = base + w * 4 + p;
      int q = pg >> 1;
      tab4[pg] = make_float4(1.0f / (sd * sd), mu, disc_mu[q], diff_mu[q]);
    }
  }
}

// ---------------------------------------------------------------------------
// K2: fused gather + backward + forward scan. Wave per user (4096 waves,
// 16/CU). All per-step data pre-gathered into registers (lane s holds step
// i*64+s); chains use readlane + per-lane select only — no global load in
// any chain.  (UNCHANGED from R3 — passed with absmax 0.1035.)
// ---------------------------------------------------------------------------
__global__ __launch_bounds__(256) void scan_kernel(
    const int* __restrict__ q_id, const int* __restrict__ resp,
    const float4* __restrict__ tab4, const int* __restrict__ kc_of_q,
    float* __restrict__ out) {
  const int lane = threadIdx.x & 63;
  const int u = (blockIdx.x << 2) | (threadIdx.x >> 6);  // wave id == user

  // ---- phase 0: gather 200 steps into 4 register tiles (tail tile = 8) ----
  float tr[4], tmu[4], tts[4], ttd[4];
  int tkc[4];
#pragma unroll
  for (int i = 0; i < 4; ++i) {
    int t = i * 64 + lane;
    int tc = t < T_ ? t : T_ - 1;       // clamp: avoids OOB; lanes>=8 of tile3 unused
    int q = q_id[u * T_ + tc];          // coalesced
    int rp = resp[u * T_ + tc];         // coalesced
    float4 f = tab4[q * 2 + rp];        // L2-resident 320KB table
    tr[i] = f.x;   // r
    tmu[i] = f.y;  // mu
    tts[i] = f.z;  // ts
    ttd[i] = f.w;  // td
    tkc[i] = kc_of_q[q];
  }

  // ---- phase 1: backward recursion t = 199..0 (wave-scalar chain) ----
  // b_t = 1/(2 + r_t - b_next); c_t = b_t*(c_next + r_t*mu_t)
  float b = 1.0f, c = 0.0f;
#define BWD_STEP(i, s)                                   \
  {                                                      \
    float r_ = rlanef(tr[i], s);                         \
    float m_ = rlanef(tmu[i], s);                        \
    float x_ = 2.0f + r_ - b;                            \
    float ib = __builtin_amdgcn_rcpf(x_);                \
    ib = ib * (2.0f - x_ * ib); /* Newton step */        \
    b = ib;                                              \
    c = b * fmaf(r_, m_, c);                             \
    tr[i] = (lane == (s)) ? b : tr[i];                   \
    tmu[i] = (lane == (s)) ? c : tmu[i];                 \
  }
#pragma unroll
  for (int s = 7; s >= 0; --s) BWD_STEP(3, s)
#pragma unroll
  for (int s = 63; s >= 0; --s) BWD_STEP(2, s)
#pragma unroll
  for (int s = 63; s >= 0; --s) BWD_STEP(1, s)
#pragma unroll
  for (int s = 63; s >= 0; --s) BWD_STEP(0, s)
#undef BWD_STEP

  // ---- phase 2: forward KC scan t = 0..199 (wave-scalar chain) ----
  float curr = 0.0f;
  float* logits = out;
  float* last = out + (size_t)U_ * T_;

#define FWD_STEP(i, s)                                    \
  {                                                       \
    float b_ = rlanef(tr[i], s);                          \
    float c_ = rlanef(tmu[i], s);                         \
    int kc_ = rlanei(tkc[i], s);                          \
    float ts_ = rlanef(tts[i], s);                        \
    float td_ = rlanef(ttd[i], s);                        \
    float prev = rlanef(curr, kc_);                       \
    float ab = fmaf(b_, prev, c_);                        \
    curr = (lane == kc_) ? ab : curr;                     \
    float lg = ts_ * (ab - td_);                          \
    lsave = (lane == (s)) ? lg : lsave;                   \
  }
  {
    float lsave = 0.0f;
#pragma unroll
    for (int s = 0; s < 64; ++s) FWD_STEP(0, s)
    logits[u * T_ + lane] = lsave;
  }
  {
    float lsave = 0.0f;
#pragma unroll
    for (int s = 0; s < 64; ++s) FWD_STEP(1, s)
    logits[u * T_ + 64 + lane] = lsave;
  }
  {
    float lsave = 0.0f;
#pragma unroll
    for (int s = 0; s < 64; ++s) FWD_STEP(2, s)
    logits[u * T_ + 128 + lane] = lsave;
  }
  {
    float lsave = 0.0f;
#pragma unroll
    for (int s = 0; s < 8; ++s) FWD_STEP(3, s)
    if (lane < 8) logits[u * T_ + 192 + lane] = lsave;
  }
#undef FWD_STEP

  last[u * K_ + lane] = curr;  // last_ability_kc (U, K=64)
}

// ---------------------------------------------------------------------------
extern "C" void kernel_launch(void* const* d_in, const int* in_sizes, int n_in,
                              void* d_out, int out_size, void* d_ws,
                              size_t ws_size, hipStream_t stream) {
  // setup_inputs order:
  // 0 mask 1 q_id(i32,U*T) 2 kmap(bool,Q*K) 3 resp(i32) 4 diff_mu 5 disc_mu
  // 6 W1 7 b1 8 W2 9 b2 10 W3 11 b3
  const int* q_id = (const int*)d_in[1];
  const unsigned char* kmap = (const unsigned char*)d_in[2];
  const int* resp = (const int*)d_in[3];
  const float* diff_mu = (const float*)d_in[4];
  const float* disc_mu = (const float*)d_in[5];
  const float* W1 = (const float*)d_in[6];
  const float* b1 = (const float*)d_in[7];
  const float* W2 = (const float*)d_in[8];
  const float* b2 = (const float*)d_in[9];
  const float* W3 = (const float*)d_in[10];
  const float* b3 = (const float*)d_in[11];
  float* out = (float*)d_out;
  char* ws = (char*)d_ws;

  auto align512 = [](size_t x) { return (x + 511) & ~(size_t)511; };
  size_t o = 0;
  float4* tab4 = (float4*)(ws + o);  o = align512(o + (size_t)2 * Q_ * 16);
  int* kc_of_q = (int*)(ws + o);     o = align512(o + (size_t)Q_ * 4);
  (void)ws_size; (void)in_sizes; (void)n_in; (void)out_size;

  mlp_table_kernel<<<1250, 256, 0, stream>>>(diff_mu, disc_mu, W1, b1, W2, b2,
                                             W3, b3, kmap, tab4, kc_of_q);
  scan_kernel<<<U_ / 4, 256, 0, stream>>>(q_id, resp, tab4, kc_of_q, out);
}

// Round 5
// 141.083 us; speedup vs baseline: 1.7190x; 1.0905x over previous
//
#include <hip/hip_runtime.h>
#include <math.h>

#define U_ 4096
#define T_ 200
#define K_ 64
#define Q_ 10000
#define H_ 128
#define UPB 16  // users per block in scan2

__device__ __forceinline__ float gelu_f(float x) {
  // exact erf GELU (matches jax.nn.gelu approximate=False)
  return 0.5f * x * (1.0f + erff(x * 0.70710678118654752440f));
}

// ---------------------------------------------------------------------------
// K1: MLP table over (q, resp) -> tab4[2q+rp] = (r, mu, ts, td)
//     plus fused kc_of_q = argmax_k kmap[q][k] (one-hot).
// UNCHANGED from R4 (spill fix: launch_bounds(256,4) + unroll_count(8)).
// ---------------------------------------------------------------------------
__global__ __launch_bounds__(256, 4) void mlp_table_kernel(
    const float* __restrict__ diff_mu, const float* __restrict__ disc_mu,
    const float* __restrict__ W1, const float* __restrict__ b1,
    const float* __restrict__ W2, const float* __restrict__ b2,
    const float* __restrict__ W3, const float* __restrict__ b3,
    const unsigned char* __restrict__ kmap,
    float4* __restrict__ tab4, int* __restrict__ kc_of_q) {
  __shared__ float W2s[64 * H_];     // 32 KB: one half of W2 at a time
  __shared__ float h1buf[16][H_];    // 8 KB

  const int tid = threadIdx.x;
  const int base = blockIdx.x * 16;  // 1250*16 = 20000 exact

  for (int v = tid; v < 64 * H_; v += 256) W2s[v] = W2[v];

  if (blockIdx.x < 40) {
    int q = blockIdx.x * 256 + tid;
    if (q < Q_) {
      const unsigned char* km = kmap + (size_t)q * K_;
      int kc = 0;
#pragma unroll
      for (int k = 0; k < K_; ++k)
        if (km[k]) kc = k;  // one-hot -> single set index
      kc_of_q[q] = kc;
    }
  }

  // layer 1
  for (int v = tid; v < 16 * H_; v += 256) {
    int pl = v >> 7, j = v & 127;
    int pg = base + pl;
    int q = pg >> 1;
    float rf = (float)(pg & 1);
    float td = diff_mu[q], ts = disc_mu[q];
    float a = b1[j];
    a += td * W1[j];
    a += ts * W1[H_ + j];
    a += rf * W1[2 * H_ + j];
    h1buf[pl][j] = gelu_f(a);
  }
  __syncthreads();

  // layer 2: wave w handles pairs 4w..4w+3; lane j -> outputs j, j+64
  const int w = tid >> 6, lane = tid & 63;
  float a0[4] = {0.f, 0.f, 0.f, 0.f}, a1[4] = {0.f, 0.f, 0.f, 0.f};
  const float* h1w = &h1buf[w * 4][0];

#pragma clang loop unroll_count(8)
  for (int k = 0; k < 64; ++k) {
    float w0 = W2s[k * H_ + lane];
    float w1 = W2s[k * H_ + lane + 64];
#pragma unroll
    for (int p = 0; p < 4; ++p) {
      float hv = h1w[p * H_ + k];
      a0[p] = fmaf(w0, hv, a0[p]);
      a1[p] = fmaf(w1, hv, a1[p]);
    }
  }
  __syncthreads();
  for (int v = tid; v < 64 * H_; v += 256) W2s[v] = W2[64 * H_ + v];
  __syncthreads();
#pragma clang loop unroll_count(8)
  for (int k = 0; k < 64; ++k) {
    float w0 = W2s[k * H_ + lane];
    float w1 = W2s[k * H_ + lane + 64];
#pragma unroll
    for (int p = 0; p < 4; ++p) {
      float hv = h1w[p * H_ + 64 + k];
      a0[p] = fmaf(w0, hv, a0[p]);
      a1[p] = fmaf(w1, hv, a1[p]);
    }
  }

  // layer 3 + head math
  float w30a = W3[lane * 2 + 0], w31a = W3[lane * 2 + 1];
  float w30b = W3[(lane + 64) * 2 + 0], w31b = W3[(lane + 64) * 2 + 1];
  float b2a = b2[lane], b2b = b2[lane + 64];
  float b30 = b3[0], b31 = b3[1];
#pragma unroll
  for (int p = 0; p < 4; ++p) {
    float h2a = gelu_f(a0[p] + b2a);
    float h2b = gelu_f(a1[p] + b2b);
    float s0 = h2a * w30a + h2b * w30b;
    float s1 = h2a * w31a + h2b * w31b;
#pragma unroll
    for (int off = 32; off > 0; off >>= 1) {
      s0 += __shfl_xor(s0, off, 64);
      s1 += __shfl_xor(s1, off, 64);
    }
    if (lane == 0) {
      float mu = gelu_f(s0 + b30);
      float lv = gelu_f(s1 + b31);
      float sd = fmaxf(expf(0.5f * lv), 1e-8f);
      int pg = base + w * 4 + p;
      int q = pg >> 1;
      tab4[pg] = make_float4(1.0f / (sd * sd), mu, disc_mu[q], diff_mu[q]);
    }
  }
}

// ---------------------------------------------------------------------------
// K2 (R5 rewrite): lane-per-user scan. 256 blocks x 16 users. Chains run on
// wave 0 with lane = user: each chain instruction advances 16 users at once
// (R4's wave-scalar version spent ~11 wave-wide instrs per single user-step:
// 85k busy cycles/SIMD, 53us, VALUBusy 67% = issue-bound).
// LDS (t,u) layout, +1 pad on the u stride.
// ---------------------------------------------------------------------------
__global__ __launch_bounds__(256) void scan2_kernel(
    const int* __restrict__ q_id, const int* __restrict__ resp,
    const float4* __restrict__ tab4, const int* __restrict__ kc_of_q,
    float* __restrict__ out) {
  __shared__ float2 bcs[T_ * (UPB + 1)];    // [t][u], stride 17: (r,mu)->(b,c)->ability
  __shared__ unsigned char kcs[T_ * UPB];   // [t][u], stride 16
  __shared__ float states[UPB * (K_ + 1)];  // [u][kc], stride 65

  const int tid = threadIdx.x;
  const int lane = tid & 63;
  const int wv = tid >> 6;
  const int u0 = blockIdx.x * UPB;

  for (int v = tid; v < UPB * (K_ + 1); v += 256) states[v] = 0.0f;

  // ---- phase 0: gather + transpose (4 waves x 4 users x 4 t-tiles) ----
  for (int uu = 0; uu < 4; ++uu) {
    const int ul = wv * 4 + uu;
    const int* qrow = q_id + (size_t)(u0 + ul) * T_;
    const int* rrow = resp + (size_t)(u0 + ul) * T_;
#pragma unroll
    for (int tile = 0; tile < 4; ++tile) {
      int t = tile * 64 + lane;
      if (t < T_) {
        int q = qrow[t];                       // coalesced
        int rp = rrow[t];                      // coalesced
        float4 f = tab4[q * 2 + rp];           // L2-resident 320 KB
        bcs[t * (UPB + 1) + ul] = make_float2(f.x, f.y);  // (r, mu)
        kcs[t * UPB + ul] = (unsigned char)kc_of_q[q];
      }
    }
  }
  __syncthreads();

  // ---- chains on wave 0, lane = user ----
  if (wv == 0) {
    const bool act = lane < UPB;
    const int ll = act ? lane : 0;  // clamped index for inactive lanes

    // backward: t = 199..0. b = 1/(2 + r - b_next); c = b*(c_next + r*mu)
    float b = 1.0f, c = 0.0f;
#pragma unroll 4
    for (int t = T_ - 1; t >= 0; --t) {
      float2 rm_ = bcs[t * (UPB + 1) + ll];  // static addr: hoistable
      float x_ = 2.0f + rm_.x - b;
      float ib = __builtin_amdgcn_rcpf(x_);
      ib = ib * (2.0f - x_ * ib);  // Newton step (same math as R3/R4: passed)
      b = ib;
      c = b * fmaf(rm_.x, rm_.y, c);
      if (act) bcs[t * (UPB + 1) + lane] = make_float2(b, c);
    }

    // forward: t = 0..199. per-lane KC state in LDS.
#pragma unroll 2
    for (int t = 0; t < T_; ++t) {
      float2 bc_ = bcs[t * (UPB + 1) + ll];
      int kc = (int)kcs[t * UPB + ll];
      float prev = states[ll * (K_ + 1) + kc];
      float ab = fmaf(bc_.x, prev, bc_.y);
      if (act) {
        states[lane * (K_ + 1) + kc] = ab;
        bcs[t * (UPB + 1) + lane].x = ab;  // stash ability for epilogue
      }
    }
  }
  __syncthreads();

  // ---- epilogue ----
  float* logits = out;
  float* last = out + (size_t)U_ * T_;

  // logits[u][t] = ts*(ability - td); coalesced stores, ts/td re-gathered
  for (int ul = 0; ul < UPB; ++ul) {
    if (tid < T_) {
      const int gu = u0 + ul;
      int q = q_id[(size_t)gu * T_ + tid];
      int rp = resp[(size_t)gu * T_ + tid];
      float4 f = tab4[q * 2 + rp];
      float ab = bcs[tid * (UPB + 1) + ul].x;
      logits[(size_t)gu * T_ + tid] = f.z * (ab - f.w);
    }
  }
  // last_ability_kc (U, K)
  for (int v = tid; v < UPB * K_; v += 256) {
    int ul = v >> 6, kc = v & 63;
    last[(size_t)(u0 + ul) * K_ + kc] = states[ul * (K_ + 1) + kc];
  }
}

// ---------------------------------------------------------------------------
extern "C" void kernel_launch(void* const* d_in, const int* in_sizes, int n_in,
                              void* d_out, int out_size, void* d_ws,
                              size_t ws_size, hipStream_t stream) {
  // setup_inputs order:
  // 0 mask 1 q_id(i32,U*T) 2 kmap(bool,Q*K) 3 resp(i32) 4 diff_mu 5 disc_mu
  // 6 W1 7 b1 8 W2 9 b2 10 W3 11 b3
  const int* q_id = (const int*)d_in[1];
  const unsigned char* kmap = (const unsigned char*)d_in[2];
  const int* resp = (const int*)d_in[3];
  const float* diff_mu = (const float*)d_in[4];
  const float* disc_mu = (const float*)d_in[5];
  const float* W1 = (const float*)d_in[6];
  const float* b1 = (const float*)d_in[7];
  const float* W2 = (const float*)d_in[8];
  const float* b2 = (const float*)d_in[9];
  const float* W3 = (const float*)d_in[10];
  const float* b3 = (const float*)d_in[11];
  float* out = (float*)d_out;
  char* ws = (char*)d_ws;

  auto align512 = [](size_t x) { return (x + 511) & ~(size_t)511; };
  size_t o = 0;
  float4* tab4 = (float4*)(ws + o);  o = align512(o + (size_t)2 * Q_ * 16);
  int* kc_of_q = (int*)(ws + o);     o = align512(o + (size_t)Q_ * 4);
  (void)ws_size; (void)in_sizes; (void)n_in; (void)out_size;

  mlp_table_kernel<<<1250, 256, 0, stream>>>(diff_mu, disc_mu, W1, b1, W2, b2,
                                             W3, b3, kmap, tab4, kc_of_q);
  scan2_kernel<<<U_ / UPB, 256, 0, stream>>>(q_id, resp, tab4, kc_of_q, out);
}

// Round 6
// 137.029 us; speedup vs baseline: 1.7699x; 1.0296x over previous
//
#include <hip/hip_runtime.h>
#include <math.h>

#define U_ 4096
#define T_ 200
#define K_ 64
#define Q_ 10000
#define H_ 128
#define UPB 8  // users per block in scan2 (wave = user)

__device__ __forceinline__ float gelu_f(float x) {
  // exact erf GELU (matches jax.nn.gelu approximate=False)
  return 0.5f * x * (1.0f + erff(x * 0.70710678118654752440f));
}

// ---------------------------------------------------------------------------
// K1: MLP table over (q, resp) -> tab4[2q+rp] = (r, mu, ts, td)
//     plus fused kc_of_q = argmax_k kmap[q][k] (one-hot).
// UNCHANGED from R4/R5 (isolate the scan change this round).
// ---------------------------------------------------------------------------
__global__ __launch_bounds__(256, 4) void mlp_table_kernel(
    const float* __restrict__ diff_mu, const float* __restrict__ disc_mu,
    const float* __restrict__ W1, const float* __restrict__ b1,
    const float* __restrict__ W2, const float* __restrict__ b2,
    const float* __restrict__ W3, const float* __restrict__ b3,
    const unsigned char* __restrict__ kmap,
    float4* __restrict__ tab4, int* __restrict__ kc_of_q) {
  __shared__ float W2s[64 * H_];     // 32 KB: one half of W2 at a time
  __shared__ float h1buf[16][H_];    // 8 KB

  const int tid = threadIdx.x;
  const int base = blockIdx.x * 16;  // 1250*16 = 20000 exact

  for (int v = tid; v < 64 * H_; v += 256) W2s[v] = W2[v];

  if (blockIdx.x < 40) {
    int q = blockIdx.x * 256 + tid;
    if (q < Q_) {
      const unsigned char* km = kmap + (size_t)q * K_;
      int kc = 0;
#pragma unroll
      for (int k = 0; k < K_; ++k)
        if (km[k]) kc = k;  // one-hot -> single set index
      kc_of_q[q] = kc;
    }
  }

  // layer 1
  for (int v = tid; v < 16 * H_; v += 256) {
    int pl = v >> 7, j = v & 127;
    int pg = base + pl;
    int q = pg >> 1;
    float rf = (float)(pg & 1);
    float td = diff_mu[q], ts = disc_mu[q];
    float a = b1[j];
    a += td * W1[j];
    a += ts * W1[H_ + j];
    a += rf * W1[2 * H_ + j];
    h1buf[pl][j] = gelu_f(a);
  }
  __syncthreads();

  // layer 2: wave w handles pairs 4w..4w+3; lane j -> outputs j, j+64
  const int w = tid >> 6, lane = tid & 63;
  float a0[4] = {0.f, 0.f, 0.f, 0.f}, a1[4] = {0.f, 0.f, 0.f, 0.f};
  const float* h1w = &h1buf[w * 4][0];

#pragma clang loop unroll_count(8)
  for (int k = 0; k < 64; ++k) {
    float w0 = W2s[k * H_ + lane];
    float w1 = W2s[k * H_ + lane + 64];
#pragma unroll
    for (int p = 0; p < 4; ++p) {
      float hv = h1w[p * H_ + k];
      a0[p] = fmaf(w0, hv, a0[p]);
      a1[p] = fmaf(w1, hv, a1[p]);
    }
  }
  __syncthreads();
  for (int v = tid; v < 64 * H_; v += 256) W2s[v] = W2[64 * H_ + v];
  __syncthreads();
#pragma clang loop unroll_count(8)
  for (int k = 0; k < 64; ++k) {
    float w0 = W2s[k * H_ + lane];
    float w1 = W2s[k * H_ + lane + 64];
#pragma unroll
    for (int p = 0; p < 4; ++p) {
      float hv = h1w[p * H_ + 64 + k];
      a0[p] = fmaf(w0, hv, a0[p]);
      a1[p] = fmaf(w1, hv, a1[p]);
    }
  }

  // layer 3 + head math
  float w30a = W3[lane * 2 + 0], w31a = W3[lane * 2 + 1];
  float w30b = W3[(lane + 64) * 2 + 0], w31b = W3[(lane + 64) * 2 + 1];
  float b2a = b2[lane], b2b = b2[lane + 64];
  float b30 = b3[0], b31 = b3[1];
#pragma unroll
  for (int p = 0; p < 4; ++p) {
    float h2a = gelu_f(a0[p] + b2a);
    float h2b = gelu_f(a1[p] + b2b);
    float s0 = h2a * w30a + h2b * w30b;
    float s1 = h2a * w31a + h2b * w31b;
#pragma unroll
    for (int off = 32; off > 0; off >>= 1) {
      s0 += __shfl_xor(s0, off, 64);
      s1 += __shfl_xor(s1, off, 64);
    }
    if (lane == 0) {
      float mu = gelu_f(s0 + b30);
      float lv = gelu_f(s1 + b31);
      float sd = fmaxf(expf(0.5f * lv), 1e-8f);
      int pg = base + w * 4 + p;
      int q = pg >> 1;
      tab4[pg] = make_float4(1.0f / (sd * sd), mu, disc_mu[q], diff_mu[q]);
    }
  }
}

// ---------------------------------------------------------------------------
// K2 (R6 rewrite): wave = user, lane = KC forward scan.
// The forward KC-scan decomposes into 64 independent linear recurrences per
// user (state for KC k only updates when kc_t == k): per step each lane does
// x = (kc_t==lane) ? fma(b,x,c) : x with (b,c,kc) as wave-uniform LDS
// broadcasts — no LDS read-modify-write chain (R5's 200x ~250cyc lgkmcnt
// serialization), and last_ability_kc falls out of the per-lane registers.
// Backward stays lane-per-user on wave 0 (pure VALU). UPB=8, block=512,
// grid=512 -> 2 blocks/CU, 4 forward waves/SIMD.
// ---------------------------------------------------------------------------
__global__ __launch_bounds__(512) void scan2_kernel(
    const int* __restrict__ q_id, const int* __restrict__ resp,
    const float4* __restrict__ tab4, const int* __restrict__ kc_of_q,
    float* __restrict__ out) {
  __shared__ float2 bcs[T_ * (UPB + 1)];    // [t][u], u-stride 9: (r,mu)->(b,c); .x later = ability
  __shared__ unsigned char kcs[T_ * UPB];   // [t][u]

  const int tid = threadIdx.x;
  const int lane = tid & 63;
  const int ul = tid >> 6;                  // wave index = local user
  const int gu = blockIdx.x * UPB + ul;     // global user

  // ---- phase 0: each wave gathers its own user's 200 steps ----
  float tts[4], ttd[4];
  const int* qrow = q_id + (size_t)gu * T_;
  const int* rrow = resp + (size_t)gu * T_;
#pragma unroll
  for (int tile = 0; tile < 4; ++tile) {
    int t = tile * 64 + lane;
    if (t < T_) {
      int q = qrow[t];                      // coalesced
      int rp = rrow[t];                     // coalesced
      float4 f = tab4[q * 2 + rp];          // L2-resident 320 KB
      bcs[t * (UPB + 1) + ul] = make_float2(f.x, f.y);  // (r, mu)
      kcs[t * UPB + ul] = (unsigned char)kc_of_q[q];
      tts[tile] = f.z;                      // ts stays in registers
      ttd[tile] = f.w;                      // td stays in registers
    }
  }
  __syncthreads();

  // ---- phase 1: backward recursion, wave 0, lane = user (8 active) ----
  if (tid < 64) {
    const bool act = lane < UPB;
    const int ll = act ? lane : 0;
    float b = 1.0f, c = 0.0f;
#pragma unroll 8
    for (int t = T_ - 1; t >= 0; --t) {
      float2 rm_ = bcs[t * (UPB + 1) + ll];   // static offsets: prefetchable
      float x_ = 2.0f + rm_.x - b;            // 1 + r + (1 - b_next)
      float ib = __builtin_amdgcn_rcpf(x_);
      ib = ib * (2.0f - x_ * ib);             // Newton step (passing since R3)
      b = ib;
      c = b * fmaf(rm_.x, rm_.y, c);
      if (act) bcs[t * (UPB + 1) + lane] = make_float2(b, c);
    }
  }
  __syncthreads();

  // ---- phase 2: forward scan, per wave, lane = KC ----
  float x = 0.0f;  // ability state of KC == lane for this wave's user
#pragma unroll 8
  for (int t = 0; t < T_; ++t) {
    float2 bc_ = bcs[t * (UPB + 1) + ul];   // uniform -> LDS broadcast
    int kc = (int)kcs[t * UPB + ul];        // uniform
    float xn = fmaf(bc_.x, x, bc_.y);
    bool hit = (lane == kc);
    x = hit ? xn : x;
    if (hit) bcs[t * (UPB + 1) + ul].x = xn;  // ability stash (1-lane write)
  }
  __syncthreads();

  // ---- epilogue ----
  float* logits = out;
  float* last = out + (size_t)U_ * T_;
#pragma unroll
  for (int tile = 0; tile < 4; ++tile) {
    int t = tile * 64 + lane;
    if (t < T_) {
      float ab = bcs[t * (UPB + 1) + ul].x;
      logits[(size_t)gu * T_ + t] = tts[tile] * (ab - ttd[tile]);  // coalesced
    }
  }
  last[(size_t)gu * K_ + lane] = x;  // last_ability_kc straight from registers
}

// ---------------------------------------------------------------------------
extern "C" void kernel_launch(void* const* d_in, const int* in_sizes, int n_in,
                              void* d_out, int out_size, void* d_ws,
                              size_t ws_size, hipStream_t stream) {
  // setup_inputs order:
  // 0 mask 1 q_id(i32,U*T) 2 kmap(bool,Q*K) 3 resp(i32) 4 diff_mu 5 disc_mu
  // 6 W1 7 b1 8 W2 9 b2 10 W3 11 b3
  const int* q_id = (const int*)d_in[1];
  const unsigned char* kmap = (const unsigned char*)d_in[2];
  const int* resp = (const int*)d_in[3];
  const float* diff_mu = (const float*)d_in[4];
  const float* disc_mu = (const float*)d_in[5];
  const float* W1 = (const float*)d_in[6];
  const float* b1 = (const float*)d_in[7];
  const float* W2 = (const float*)d_in[8];
  const float* b2 = (const float*)d_in[9];
  const float* W3 = (const float*)d_in[10];
  const float* b3 = (const float*)d_in[11];
  float* out = (float*)d_out;
  char* ws = (char*)d_ws;

  auto align512 = [](size_t x) { return (x + 511) & ~(size_t)511; };
  size_t o = 0;
  float4* tab4 = (float4*)(ws + o);  o = align512(o + (size_t)2 * Q_ * 16);
  int* kc_of_q = (int*)(ws + o);     o = align512(o + (size_t)Q_ * 4);
  (void)ws_size; (void)in_sizes; (void)n_in; (void)out_size;

  mlp_table_kernel<<<1250, 256, 0, stream>>>(diff_mu, disc_mu, W1, b1, W2, b2,
                                             W3, b3, kmap, tab4, kc_of_q);
  scan2_kernel<<<U_ / UPB, 512, 0, stream>>>(q_id, resp, tab4, kc_of_q, out);
}